// Round 4
// baseline (458.729 us; speedup 1.0000x reference)
//
#include <hip/hip_runtime.h>
#include <hip/hip_bf16.h>
#include <hip/hip_cooperative_groups.h>

namespace cg = cooperative_groups;

#define E_N 4
#define B_N 64
#define IN_N 4096
#define H_N 4096
#define R_N 512
#define OUT_N 4096
#define TOT_N 8388608  // R*IN + H*R + R*H + OUT*R

typedef float f32x4 __attribute__((ext_vector_type(4)));
typedef short bf16x8 __attribute__((ext_vector_type(8)));

__device__ __forceinline__ unsigned short f2bf_bits(float f) {
    return __builtin_bit_cast(unsigned short, __float2bfloat16(f));
}
__device__ __forceinline__ float bfbits2f(unsigned short u) {
    return __builtin_bit_cast(float, ((unsigned)u) << 16);
}

__device__ __forceinline__ void stage16(const void* g, void* l) {
    __builtin_amdgcn_global_load_lds(
        (const __attribute__((address_space(1))) void*)g,
        (__attribute__((address_space(3))) void*)l, 16, 0, 0);
}

// One GEMM phase: C[e,b,n] = sum_k A[e?,b,k] * (W[n,k] + D[e,n,k])
// 512 blocks, tile 64 rows x 32 cols, KCH=512 in 8 K-tiles of 64.
// Identical body to the verified R3 kernel.
template<int K_TOT, int N_TOT, int KS, bool A_SHARED, bool RELU, bool OUT_BF16>
__device__ __forceinline__ void gemm_phase(
    char* smem, const __hip_bfloat16* __restrict__ A, const float* __restrict__ W,
    const float* __restrict__ D, float* __restrict__ OutF,
    __hip_bfloat16* __restrict__ OutB, int bid, int tid)
{
    constexpr int KCH = K_TOT / KS;      // 512 always
    constexpr int NT = N_TOT / 32;
    constexpr int NTILES = KCH / 64;     // 8
    float (*Wt)[64] = (float(*)[64])smem;                         // 8 KB
    float (*Dt)[64] = (float(*)[64])(smem + 8192);                // 8 KB
    __hip_bfloat16 (*At)[64] = (__hip_bfloat16(*)[64])(smem + 16384); // 8 KB

    const int ks = bid % KS;
    const int nt = (bid / KS) % NT;
    const int e  = bid / (KS * NT);
    const int l  = tid & 63;
    const int w  = tid >> 6;
    const int wn = w & 1;
    const int wm = w >> 1;
    const int lr = l & 15;
    const int lk = (l >> 4) << 3;

    const float* Wb = W + (size_t)(nt * 32) * K_TOT + ks * KCH;
    const float* Db = D + (size_t)e * TOT_N + (size_t)(nt * 32) * K_TOT + ks * KCH;
    const __hip_bfloat16* Ab = A + (A_SHARED ? (size_t)0 : (size_t)e * B_N * K_TOT)
                                 + ks * KCH;

    const char* gsrc[6];
    char* ldst[6];
    int kstep[6];
    #pragma unroll
    for (int i = 0; i < 6; ++i) {
        const int q = w * 6 + i;
        if (q < 8) {
            const int off = q * 1024 + l * 16;
            const int row = off >> 8;
            const int kb  = off & 255;
            const int skb = kb ^ ((row & 7) << 4);
            gsrc[i] = (const char*)(Wb + (size_t)row * K_TOT) + skb;
            ldst[i] = (char*)&Wt[0][0] + q * 1024;
            kstep[i] = 4;
        } else if (q < 16) {
            const int c = q - 8;
            const int off = c * 1024 + l * 16;
            const int row = off >> 8;
            const int kb  = off & 255;
            const int skb = kb ^ ((row & 7) << 4);
            gsrc[i] = (const char*)(Db + (size_t)row * K_TOT) + skb;
            ldst[i] = (char*)&Dt[0][0] + c * 1024;
            kstep[i] = 4;
        } else {
            const int c = q - 16;
            const int off = c * 1024 + l * 16;
            const int row = off >> 7;
            const int kb  = off & 127;
            const int skb = kb ^ ((row & 7) << 4);
            gsrc[i] = (const char*)(Ab + (size_t)row * K_TOT) + skb;
            ldst[i] = (char*)&At[0][0] + c * 1024;
            kstep[i] = 2;
        }
    }

    f32x4 acc[2] = {};
    const int wrow = wn * 16 + lr;
    const int wswz = (wrow & 7) << 4;
    const int arow0 = wm * 32 + lr;
    const int aswz = (arow0 & 7) << 4;

    for (int t = 0; t < NTILES; ++t) {
        const int kk = t * 64;
        #pragma unroll
        for (int i = 0; i < 6; ++i)
            stage16(gsrc[i] + kk * kstep[i], ldst[i]);
        __syncthreads();

        #pragma unroll
        for (int inner = 0; inner < 2; ++inner) {
            const int b0 = (inner * 32 + lk) * 4;
            const char* wrp = (const char*)&Wt[0][0] + wrow * 256;
            const char* drp = (const char*)&Dt[0][0] + wrow * 256;
            f32x4 w0 = *(const f32x4*)(wrp + ((b0)      ^ wswz));
            f32x4 w1 = *(const f32x4*)(wrp + ((b0 + 16) ^ wswz));
            f32x4 d0 = *(const f32x4*)(drp + ((b0)      ^ wswz));
            f32x4 d1 = *(const f32x4*)(drp + ((b0 + 16) ^ wswz));
            f32x4 s0 = w0 + d0;
            f32x4 s1 = w1 + d1;
            bf16x8 bhi, blo;
            #pragma unroll
            for (int j = 0; j < 4; ++j) {
                unsigned short h0 = f2bf_bits(s0[j]);
                bhi[j] = (short)h0;
                blo[j] = (short)f2bf_bits(s0[j] - bfbits2f(h0));
                unsigned short h1 = f2bf_bits(s1[j]);
                bhi[j + 4] = (short)h1;
                blo[j + 4] = (short)f2bf_bits(s1[j] - bfbits2f(h1));
            }
            const int ab = (inner * 32 + lk) * 2;
            #pragma unroll
            for (int mf = 0; mf < 2; ++mf) {
                const int ar = arow0 + mf * 16;
                const char* arp = (const char*)&At[0][0] + ar * 128;
                bf16x8 af = *(const bf16x8*)(arp + (ab ^ aswz));
                acc[mf] = __builtin_amdgcn_mfma_f32_16x16x32_bf16(af, bhi, acc[mf], 0, 0, 0);
                acc[mf] = __builtin_amdgcn_mfma_f32_16x16x32_bf16(af, blo, acc[mf], 0, 0, 0);
            }
        }
        __syncthreads();
    }

    const int rb = (l >> 4) * 4;
    const int nrow = nt * 32 + wrow;
    #pragma unroll
    for (int j = 0; j < 2; ++j) {
        #pragma unroll
        for (int i = 0; i < 4; ++i) {
            const int row = wm * 32 + j * 16 + rb + i;
            float v = acc[j][i];
            if (RELU) v = fmaxf(v, 0.0f);
            if (OUT_BF16) {
                OutB[(size_t)e * B_N * N_TOT + (size_t)row * N_TOT + nrow] =
                    __float2bfloat16(v);
            } else {
                OutF[(size_t)(e * KS + ks) * B_N * N_TOT + (size_t)row * N_TOT + nrow] = v;
            }
        }
    }
}

struct Params {
    const float* x;
    const float* scores;
    const float* delta;
    const float* W1;
    const float* W2;
    const float* W3;
    const float* W4;
    float* out;
    __hip_bfloat16* xb;
    __hip_bfloat16* h1b;
    __hip_bfloat16* h2b;
    __hip_bfloat16* h3b;
    float* P1;
    float* P3;
    float* P4;
};

__global__ __launch_bounds__(256, 2)
void moe_fused(Params p)
{
    __shared__ __align__(16) char smem[24576];
    cg::grid_group grid = cg::this_grid();
    const int bid = blockIdx.x;
    const int tid = threadIdx.x;
    const int gt = bid * 256 + tid;   // 131072 threads

    const float* d1 = p.delta;
    const float* d2 = d1 + (size_t)R_N * IN_N;
    const float* d3 = d2 + (size_t)H_N * R_N;
    const float* d4 = d3 + (size_t)R_N * H_N;

    // phase 0: xb = bf16(x)   (B*IN = 262144 elems, 2 per thread)
    {
        const int idx = gt * 2;
        const float2 v = *(const float2*)(p.x + idx);
        const unsigned u = ((unsigned)f2bf_bits(v.y) << 16) | f2bf_bits(v.x);
        *(unsigned*)((char*)p.xb + (size_t)idx * 2) = u;
    }
    grid.sync();

    // phase 1: L1 partials  K=4096, N=512, KS=8
    gemm_phase<IN_N, R_N, 8, true, false, false>(smem, p.xb, p.W1, d1, p.P1, nullptr, bid, tid);
    grid.sync();

    // phase 2: h1b = bf16(sum_ks P1)   (E*B*R = 131072, 1 per thread)
    {
        const int e = gt >> 15;
        const int r = gt & 32767;
        const float* base = p.P1 + (size_t)e * 8 * 32768 + r;
        float s = 0.0f;
        #pragma unroll
        for (int k = 0; k < 8; ++k) s += base[(size_t)k * 32768];
        p.h1b[gt] = __float2bfloat16(s);
    }
    grid.sync();

    // phase 3: L2  K=512, N=4096, relu -> bf16
    gemm_phase<R_N, H_N, 1, false, true, true>(smem, p.h1b, p.W2, d2, nullptr, p.h2b, bid, tid);
    grid.sync();

    // phase 4: L3 partials  K=4096, N=512, KS=8
    gemm_phase<H_N, R_N, 8, false, false, false>(smem, p.h2b, p.W3, d3, p.P3, nullptr, bid, tid);
    grid.sync();

    // phase 5: h3b = bf16(sum_ks P3)
    {
        const int e = gt >> 15;
        const int r = gt & 32767;
        const float* base = p.P3 + (size_t)e * 8 * 32768 + r;
        float s = 0.0f;
        #pragma unroll
        for (int k = 0; k < 8; ++k) s += base[(size_t)k * 32768];
        p.h3b[gt] = __float2bfloat16(s);
    }
    grid.sync();

    // phase 6: L4  K=512, N=4096 -> P4 f32
    gemm_phase<R_N, OUT_N, 1, false, false, false>(smem, p.h3b, p.W4, d4, p.P4, nullptr, bid, tid);
    grid.sync();

    // phase 7: out[b,o] = sum_e scores[e] * P4[e,b,o]   (65536 threads x f32x4)
    if (gt < 65536) {
        const int idx = gt * 4;
        f32x4 acc = {};
        #pragma unroll
        for (int e = 0; e < E_N; ++e) {
            f32x4 v = *(const f32x4*)(p.P4 + (size_t)e * (B_N * OUT_N) + idx);
            acc += p.scores[e] * v;
        }
        *(f32x4*)(p.out + idx) = acc;
    }
}

extern "C" void kernel_launch(void* const* d_in, const int* in_sizes, int n_in,
                              void* d_out, int out_size, void* d_ws, size_t ws_size,
                              hipStream_t stream)
{
    char* ws = (char*)d_ws;
    Params p;
    p.x      = (const float*)d_in[0];
    p.scores = (const float*)d_in[1];
    p.delta  = (const float*)d_in[2];
    p.W1     = (const float*)d_in[3];
    p.W2     = (const float*)d_in[4];
    p.W3     = (const float*)d_in[5];
    p.W4     = (const float*)d_in[6];
    p.out    = (float*)d_out;
    p.xb  = (__hip_bfloat16*)(ws);                    // 512 KB
    p.h1b = (__hip_bfloat16*)(ws + 524288);           // 256 KB
    p.h2b = (__hip_bfloat16*)(ws + 786432);           // 2 MB
    p.h3b = (__hip_bfloat16*)(ws + 2883584);          // 256 KB
    p.P1  = (float*)(ws + 3145728);                   // 4 MB
    p.P3  = (float*)(ws + 7340032);                   // 4 MB
    p.P4  = (float*)(ws + 11534336);                  // 4 MB

    void* args[] = { &p };
    hipLaunchCooperativeKernel((void*)moe_fused, dim3(512), dim3(256), args, 0, stream);
}

// Round 5
// 51.563 us; speedup vs baseline: 8.8966x; 8.8966x over previous
//
#include <hip/hip_runtime.h>
#include <hip/hip_bf16.h>

#define E_N 4
#define B_N 64
#define IN_N 4096
#define H_N 4096
#define R_N 512
#define OUT_N 4096
#define TOT_N 8388608  // R*IN + H*R + R*H + OUT*R

typedef float f32x4 __attribute__((ext_vector_type(4)));
typedef short bf16x8 __attribute__((ext_vector_type(8)));
typedef unsigned short u16x8 __attribute__((ext_vector_type(8)));

__device__ __forceinline__ unsigned short f2bf_bits(float f) {
    return __builtin_bit_cast(unsigned short, __float2bfloat16(f));
}
__device__ __forceinline__ float bfbits2f(unsigned short u) {
    return __builtin_bit_cast(float, ((unsigned)u) << 16);
}

__device__ __forceinline__ void stage16(const void* g, void* l) {
    __builtin_amdgcn_global_load_lds(
        (const __attribute__((address_space(1))) void*)g,
        (__attribute__((address_space(3))) void*)l, 16, 0, 0);
}

// C[e,b,n] = sum_k A[e?,b,k] * (W[n,k] + D[e,n,k])
// Block: 256 thr / 4 waves, tile 64 rows x 32 cols, KCH=512 in 8 K-tiles of 64.
// DOUBLE-BUFFERED: stage tile t+1 (global_load_lds w16, pre-swizzled source)
// before computing tile t; ONE __syncthreads per tile (drains vmcnt + WAR guard).
// Weights split hi/lo bf16 for precision; fragment reads XOR-swizzled.
template<int K_TOT, int N_TOT, int KS, bool A_SHARED, bool RELU, bool OUT_BF16>
__global__ __launch_bounds__(256, 2)
void gemm_layer(const __hip_bfloat16* __restrict__ A, const float* __restrict__ W,
                const float* __restrict__ D, float* __restrict__ OutF,
                __hip_bfloat16* __restrict__ OutB)
{
    constexpr int KCH = K_TOT / KS;      // 512 for every layer
    constexpr int NT = N_TOT / 32;
    constexpr int NTILES = KCH / 64;     // 8
    constexpr int BUFSZ = 24576;
    __shared__ __align__(16) char smem[2 * BUFSZ];  // [buf][ Wt 8K | Dt 8K | At 8K ]

    const int bid = blockIdx.x;
    const int ks = bid % KS;
    const int nt = (bid / KS) % NT;
    const int e  = bid / (KS * NT);
    const int tid = threadIdx.x;
    const int l  = tid & 63;
    const int w  = tid >> 6;
    const int wn = w & 1;
    const int wm = w >> 1;
    const int lr = l & 15;
    const int lk = (l >> 4) << 3;

    const float* Wb = W + (size_t)(nt * 32) * K_TOT + ks * KCH;
    const float* Db = D + (size_t)e * TOT_N + (size_t)(nt * 32) * K_TOT + ks * KCH;
    const __hip_bfloat16* Ab = A + (A_SHARED ? (size_t)0 : (size_t)e * B_N * K_TOT)
                                 + ks * KCH;

    // 24 1-KB staging chunks: q 0-7 Wt, 8-15 Dt, 16-23 At. 6 per wave.
    const char* gsrc[6];
    int loff[6];     // LDS offset within buffer
    int kstep[6];
    #pragma unroll
    for (int i = 0; i < 6; ++i) {
        const int q = w * 6 + i;
        if (q < 8) {
            const int off = q * 1024 + l * 16;
            const int row = off >> 8;            // 256 B per f32 row of 64
            const int kb  = off & 255;
            gsrc[i] = (const char*)(Wb + (size_t)row * K_TOT) + (kb ^ ((row & 7) << 4));
            loff[i] = q * 1024;
            kstep[i] = 4;
        } else if (q < 16) {
            const int c = q - 8;
            const int off = c * 1024 + l * 16;
            const int row = off >> 8;
            const int kb  = off & 255;
            gsrc[i] = (const char*)(Db + (size_t)row * K_TOT) + (kb ^ ((row & 7) << 4));
            loff[i] = 8192 + c * 1024;
            kstep[i] = 4;
        } else {
            const int c = q - 16;
            const int off = c * 1024 + l * 16;
            const int row = off >> 7;            // 128 B per bf16 row of 64
            const int kb  = off & 127;
            gsrc[i] = (const char*)(Ab + (size_t)row * K_TOT) + (kb ^ ((row & 7) << 4));
            loff[i] = 16384 + c * 1024;
            kstep[i] = 2;
        }
    }

    f32x4 acc[2] = {};
    const int wrow = wn * 16 + lr;
    const int wswz = (wrow & 7) << 4;
    const int arow0 = wm * 32 + lr;
    const int aswz = (arow0 & 7) << 4;

    // prologue: stage tile 0 into buf 0
    #pragma unroll
    for (int i = 0; i < 6; ++i)
        stage16(gsrc[i], smem + loff[i]);
    __syncthreads();

    for (int t = 0; t < NTILES; ++t) {
        // fire-and-forget next tile into the other buffer
        if (t + 1 < NTILES) {
            const int kk = (t + 1) * 64;
            char* b = smem + ((t + 1) & 1) * BUFSZ;
            #pragma unroll
            for (int i = 0; i < 6; ++i)
                stage16(gsrc[i] + kk * kstep[i], b + loff[i]);
        }

        const char* buf = smem + (t & 1) * BUFSZ;
        #pragma unroll
        for (int inner = 0; inner < 2; ++inner) {
            const int b0 = (inner * 32 + lk) * 4;
            const char* wrp = buf + wrow * 256;
            const char* drp = buf + 8192 + wrow * 256;
            f32x4 w0 = *(const f32x4*)(wrp + ((b0)      ^ wswz));
            f32x4 w1 = *(const f32x4*)(wrp + ((b0 + 16) ^ wswz));
            f32x4 d0 = *(const f32x4*)(drp + ((b0)      ^ wswz));
            f32x4 d1 = *(const f32x4*)(drp + ((b0 + 16) ^ wswz));
            f32x4 s0 = w0 + d0;
            f32x4 s1 = w1 + d1;
            bf16x8 bhi, blo;
            #pragma unroll
            for (int j = 0; j < 4; ++j) {
                unsigned short h0 = f2bf_bits(s0[j]);
                bhi[j] = (short)h0;
                blo[j] = (short)f2bf_bits(s0[j] - bfbits2f(h0));
                unsigned short h1 = f2bf_bits(s1[j]);
                bhi[j + 4] = (short)h1;
                blo[j + 4] = (short)f2bf_bits(s1[j] - bfbits2f(h1));
            }
            const int ab = (inner * 32 + lk) * 2;
            #pragma unroll
            for (int mf = 0; mf < 2; ++mf) {
                const int ar = arow0 + mf * 16;
                const char* arp = buf + 16384 + ar * 128;
                bf16x8 af = *(const bf16x8*)(arp + (ab ^ aswz));
                acc[mf] = __builtin_amdgcn_mfma_f32_16x16x32_bf16(af, bhi, acc[mf], 0, 0, 0);
                acc[mf] = __builtin_amdgcn_mfma_f32_16x16x32_bf16(af, blo, acc[mf], 0, 0, 0);
            }
        }
        // one barrier per tile: drains vmcnt (next tile staged) + lgkm, and
        // guards WAR before iteration t+1 overwrites buf[(t+2)&1] == buf[t&1]... 
        // (stage at t+1 writes buf[t&1]? no: writes buf[(t+2)&1]; the barrier
        //  separates iteration t's reads of buf[t&1] from t+1's stage into it.)
        __syncthreads();
    }

    // C/D layout: col = l&15 (== nrow), row(frag) = (l>>4)*4 + i
    const int rb = (l >> 4) * 4;
    const int nrow = nt * 32 + wrow;
    #pragma unroll
    for (int j = 0; j < 2; ++j) {
        #pragma unroll
        for (int i = 0; i < 4; ++i) {
            const int row = wm * 32 + j * 16 + rb + i;
            float v = acc[j][i];
            if (RELU) v = fmaxf(v, 0.0f);
            if (OUT_BF16) {
                OutB[(size_t)e * B_N * N_TOT + (size_t)row * N_TOT + nrow] =
                    __float2bfloat16(v);
            } else {
                OutF[(size_t)(e * KS + ks) * B_N * N_TOT + (size_t)row * N_TOT + nrow] = v;
            }
        }
    }
}

// H[e,b,n] = bf16( sum_ks P[e,ks,b,n] )
template<int KS, int TOTAL, int BN>
__global__ __launch_bounds__(256)
void reduce_ks_bf16(const float* __restrict__ P, __hip_bfloat16* __restrict__ H)
{
    const int t = blockIdx.x * blockDim.x + threadIdx.x;
    const int idx = t * 8;
    const int e = idx / BN;
    const int r = idx - e * BN;
    const float* base = P + (size_t)e * KS * BN + r;
    f32x4 s0 = {}, s1 = {};
    #pragma unroll
    for (int k = 0; k < KS; ++k) {
        s0 += *(const f32x4*)(base + (size_t)k * BN);
        s1 += *(const f32x4*)(base + (size_t)k * BN + 4);
    }
    u16x8 o;
    #pragma unroll
    for (int j = 0; j < 4; ++j) {
        o[j]     = f2bf_bits(s0[j]);
        o[j + 4] = f2bf_bits(s1[j]);
    }
    *(u16x8*)(H + idx) = o;
}

__global__ __launch_bounds__(256)
void convert_bf16(const float* __restrict__ X, __hip_bfloat16* __restrict__ Xb)
{
    const int t = blockIdx.x * blockDim.x + threadIdx.x;
    const int idx = t * 8;
    f32x4 a0 = *(const f32x4*)(X + idx);
    f32x4 a1 = *(const f32x4*)(X + idx + 4);
    u16x8 o;
    #pragma unroll
    for (int j = 0; j < 4; ++j) {
        o[j]     = f2bf_bits(a0[j]);
        o[j + 4] = f2bf_bits(a1[j]);
    }
    *(u16x8*)(Xb + idx) = o;
}

__global__ __launch_bounds__(256)
void reduce_experts(const float* __restrict__ P, const float* __restrict__ scores,
                    float* __restrict__ out)
{
    const int t = blockIdx.x * blockDim.x + threadIdx.x;
    const int idx = t * 4;
    f32x4 acc = {};
    #pragma unroll
    for (int e = 0; e < E_N; ++e) {
        f32x4 v = *(const f32x4*)(P + (size_t)e * (B_N * OUT_N) + idx);
        acc += scores[e] * v;
    }
    *(f32x4*)(out + idx) = acc;
}

extern "C" void kernel_launch(void* const* d_in, const int* in_sizes, int n_in,
                              void* d_out, int out_size, void* d_ws, size_t ws_size,
                              hipStream_t stream)
{
    const float* x      = (const float*)d_in[0];
    const float* scores = (const float*)d_in[1];
    const float* delta  = (const float*)d_in[2];
    const float* W1     = (const float*)d_in[3];
    const float* W2     = (const float*)d_in[4];
    const float* W3     = (const float*)d_in[5];
    const float* W4     = (const float*)d_in[6];
    float* out = (float*)d_out;

    char* ws = (char*)d_ws;
    __hip_bfloat16* xb  = (__hip_bfloat16*)(ws);                    // 512 KB
    __hip_bfloat16* h1b = (__hip_bfloat16*)(ws + 524288);           // 256 KB
    __hip_bfloat16* h2b = (__hip_bfloat16*)(ws + 786432);           // 2 MB
    __hip_bfloat16* h3b = (__hip_bfloat16*)(ws + 2883584);          // 256 KB
    float* P1 = (float*)(ws + 3145728);                             // 4 MB
    float* P3 = (float*)(ws + 7340032);                             // 4 MB
    float* P4 = (float*)(ws + 11534336);                            // 4 MB

    const float* d1 = delta;
    const float* d2 = d1 + (size_t)R_N * IN_N;
    const float* d3 = d2 + (size_t)H_N * R_N;
    const float* d4 = d3 + (size_t)R_N * H_N;

    convert_bf16<<<dim3(B_N * IN_N / 8 / 256), dim3(256), 0, stream>>>(x, xb);

    // L1: K=4096, N=512, KS=8
    gemm_layer<IN_N, R_N, 8, true, false, false>
        <<<dim3(E_N * (R_N / 32) * 8), dim3(256), 0, stream>>>(xb, W1, d1, P1, nullptr);
    reduce_ks_bf16<8, E_N * B_N * R_N, B_N * R_N>
        <<<dim3(E_N * B_N * R_N / 8 / 256), dim3(256), 0, stream>>>(P1, h1b);

    // L2: K=512, N=4096, relu -> bf16
    gemm_layer<R_N, H_N, 1, false, true, true>
        <<<dim3(E_N * (H_N / 32)), dim3(256), 0, stream>>>(h1b, W2, d2, nullptr, h2b);

    // L3: K=4096, N=512, KS=8
    gemm_layer<H_N, R_N, 8, false, false, false>
        <<<dim3(E_N * (R_N / 32) * 8), dim3(256), 0, stream>>>(h2b, W3, d3, P3, nullptr);
    reduce_ks_bf16<8, E_N * B_N * R_N, B_N * R_N>
        <<<dim3(E_N * B_N * R_N / 8 / 256), dim3(256), 0, stream>>>(P3, h3b);

    // L4: K=512, N=4096
    gemm_layer<R_N, OUT_N, 1, false, false, false>
        <<<dim3(E_N * (OUT_N / 32)), dim3(256), 0, stream>>>(h3b, W4, d4, P4, nullptr);

    reduce_experts<<<dim3(B_N * OUT_N / 4 / 256), dim3(256), 0, stream>>>(P4, scores, out);
}

// Round 6
// 51.434 us; speedup vs baseline: 8.9188x; 1.0025x over previous
//
#include <hip/hip_runtime.h>
#include <hip/hip_bf16.h>

#define E_N 4
#define B_N 64
#define IN_N 4096
#define H_N 4096
#define R_N 512
#define OUT_N 4096
#define TOT_N 8388608  // R*IN + H*R + R*H + OUT*R

typedef float f32x4 __attribute__((ext_vector_type(4)));
typedef short bf16x8 __attribute__((ext_vector_type(8)));

__device__ __forceinline__ unsigned short f2bf_bits(float f) {
    return __builtin_bit_cast(unsigned short, __float2bfloat16(f));
}
__device__ __forceinline__ float bfbits2f(unsigned short u) {
    return __builtin_bit_cast(float, ((unsigned)u) << 16);
}

__device__ __forceinline__ void stage16(const void* g, void* l) {
    __builtin_amdgcn_global_load_lds(
        (const __attribute__((address_space(1))) void*)g,
        (__attribute__((address_space(3))) void*)l, 16, 0, 0);
}

// C[e,b,n] = sum_k A[e?,b,k] * (W[n,k] + D[e,n,k])
// Block: 256 thr / 4 waves, tile 64 rows x 32 cols, KCH=512 in 8 K-tiles of 64.
// Double-buffered global_load_lds staging (verified R5 body, unchanged).
template<int K_TOT, int N_TOT, int KS, bool A_SHARED, bool RELU, bool OUT_BF16>
__global__ __launch_bounds__(256, 2)
void gemm_layer(const __hip_bfloat16* __restrict__ A, const float* __restrict__ W,
                const float* __restrict__ D, float* __restrict__ OutF,
                __hip_bfloat16* __restrict__ OutB)
{
    constexpr int KCH = K_TOT / KS;      // 512 for every layer
    constexpr int NT = N_TOT / 32;
    constexpr int NTILES = KCH / 64;     // 8
    constexpr int BUFSZ = 24576;
    __shared__ __align__(16) char smem[2 * BUFSZ];  // [buf][ Wt 8K | Dt 8K | At 8K ]

    const int bid = blockIdx.x;
    const int ks = bid % KS;
    const int nt = (bid / KS) % NT;
    const int e  = bid / (KS * NT);
    const int tid = threadIdx.x;
    const int l  = tid & 63;
    const int w  = tid >> 6;
    const int wn = w & 1;
    const int wm = w >> 1;
    const int lr = l & 15;
    const int lk = (l >> 4) << 3;

    const float* Wb = W + (size_t)(nt * 32) * K_TOT + ks * KCH;
    const float* Db = D + (size_t)e * TOT_N + (size_t)(nt * 32) * K_TOT + ks * KCH;
    const __hip_bfloat16* Ab = A + (A_SHARED ? (size_t)0 : (size_t)e * B_N * K_TOT)
                                 + ks * KCH;

    const char* gsrc[6];
    int loff[6];
    int kstep[6];
    #pragma unroll
    for (int i = 0; i < 6; ++i) {
        const int q = w * 6 + i;
        if (q < 8) {
            const int off = q * 1024 + l * 16;
            const int row = off >> 8;
            const int kb  = off & 255;
            gsrc[i] = (const char*)(Wb + (size_t)row * K_TOT) + (kb ^ ((row & 7) << 4));
            loff[i] = q * 1024;
            kstep[i] = 4;
        } else if (q < 16) {
            const int c = q - 8;
            const int off = c * 1024 + l * 16;
            const int row = off >> 8;
            const int kb  = off & 255;
            gsrc[i] = (const char*)(Db + (size_t)row * K_TOT) + (kb ^ ((row & 7) << 4));
            loff[i] = 8192 + c * 1024;
            kstep[i] = 4;
        } else {
            const int c = q - 16;
            const int off = c * 1024 + l * 16;
            const int row = off >> 7;
            const int kb  = off & 127;
            gsrc[i] = (const char*)(Ab + (size_t)row * K_TOT) + (kb ^ ((row & 7) << 4));
            loff[i] = 16384 + c * 1024;
            kstep[i] = 2;
        }
    }

    f32x4 acc[2] = {};
    const int wrow = wn * 16 + lr;
    const int wswz = (wrow & 7) << 4;
    const int arow0 = wm * 32 + lr;
    const int aswz = (arow0 & 7) << 4;

    #pragma unroll
    for (int i = 0; i < 6; ++i)
        stage16(gsrc[i], smem + loff[i]);
    __syncthreads();

    for (int t = 0; t < NTILES; ++t) {
        if (t + 1 < NTILES) {
            const int kk = (t + 1) * 64;
            char* b = smem + ((t + 1) & 1) * BUFSZ;
            #pragma unroll
            for (int i = 0; i < 6; ++i)
                stage16(gsrc[i] + kk * kstep[i], b + loff[i]);
        }

        const char* buf = smem + (t & 1) * BUFSZ;
        #pragma unroll
        for (int inner = 0; inner < 2; ++inner) {
            const int b0 = (inner * 32 + lk) * 4;
            const char* wrp = buf + wrow * 256;
            const char* drp = buf + 8192 + wrow * 256;
            f32x4 w0 = *(const f32x4*)(wrp + ((b0)      ^ wswz));
            f32x4 w1 = *(const f32x4*)(wrp + ((b0 + 16) ^ wswz));
            f32x4 d0 = *(const f32x4*)(drp + ((b0)      ^ wswz));
            f32x4 d1 = *(const f32x4*)(drp + ((b0 + 16) ^ wswz));
            f32x4 s0 = w0 + d0;
            f32x4 s1 = w1 + d1;
            bf16x8 bhi, blo;
            #pragma unroll
            for (int j = 0; j < 4; ++j) {
                unsigned short h0 = f2bf_bits(s0[j]);
                bhi[j] = (short)h0;
                blo[j] = (short)f2bf_bits(s0[j] - bfbits2f(h0));
                unsigned short h1 = f2bf_bits(s1[j]);
                bhi[j + 4] = (short)h1;
                blo[j + 4] = (short)f2bf_bits(s1[j] - bfbits2f(h1));
            }
            const int ab = (inner * 32 + lk) * 2;
            #pragma unroll
            for (int mf = 0; mf < 2; ++mf) {
                const int ar = arow0 + mf * 16;
                const char* arp = buf + 16384 + ar * 128;
                bf16x8 af = *(const bf16x8*)(arp + (ab ^ aswz));
                acc[mf] = __builtin_amdgcn_mfma_f32_16x16x32_bf16(af, bhi, acc[mf], 0, 0, 0);
                acc[mf] = __builtin_amdgcn_mfma_f32_16x16x32_bf16(af, blo, acc[mf], 0, 0, 0);
            }
        }
        __syncthreads();
    }

    const int rb = (l >> 4) * 4;
    const int nrow = nt * 32 + wrow;
    #pragma unroll
    for (int j = 0; j < 2; ++j) {
        #pragma unroll
        for (int i = 0; i < 4; ++i) {
            const int row = wm * 32 + j * 16 + rb + i;
            float v = acc[j][i];
            if (RELU) v = fmaxf(v, 0.0f);
            if (OUT_BF16) {
                OutB[(size_t)e * B_N * N_TOT + (size_t)row * N_TOT + nrow] =
                    __float2bfloat16(v);
            } else {
                OutF[(size_t)(e * KS + ks) * B_N * N_TOT + (size_t)row * N_TOT + nrow] = v;
            }
        }
    }
}

// H[e,b,n] = bf16( sum_ks P[e,ks,b,n] )  — 1 output/thread, 512 blocks (full GPU)
template<int KS, int BN>
__global__ __launch_bounds__(256)
void reduce_ks_bf16(const float* __restrict__ P, __hip_bfloat16* __restrict__ H)
{
    const int gt = blockIdx.x * 256 + threadIdx.x;   // 0 .. E*BN-1
    const int e = gt / BN;
    const int r = gt - e * BN;
    const float* base = P + (size_t)e * KS * BN + r;
    float s = 0.0f;
    #pragma unroll
    for (int k = 0; k < KS; ++k) s += base[(size_t)k * BN];
    H[gt] = __float2bfloat16(s);
}

// xb = bf16(x) — 2 f32 / thread, 512 blocks
__global__ __launch_bounds__(256)
void convert_bf16(const float* __restrict__ X, __hip_bfloat16* __restrict__ Xb)
{
    const int gt = blockIdx.x * 256 + threadIdx.x;
    const int idx = gt * 2;
    const float2 v = *(const float2*)(X + idx);
    const unsigned u = ((unsigned)f2bf_bits(v.y) << 16) | f2bf_bits(v.x);
    *(unsigned*)((char*)Xb + (size_t)idx * 2) = u;
}

// out[b,o] = sum_e scores[e] * P[e,b,o] — f32x2 / thread, 512 blocks
__global__ __launch_bounds__(256)
void reduce_experts(const float* __restrict__ P, const float* __restrict__ scores,
                    float* __restrict__ out)
{
    const int gt = blockIdx.x * 256 + threadIdx.x;
    const int idx = gt * 2;
    float2 acc = {0.0f, 0.0f};
    #pragma unroll
    for (int e = 0; e < E_N; ++e) {
        const float2 v = *(const float2*)(P + (size_t)e * (B_N * OUT_N) + idx);
        const float s = scores[e];
        acc.x += s * v.x;
        acc.y += s * v.y;
    }
    *(float2*)(out + idx) = acc;
}

extern "C" void kernel_launch(void* const* d_in, const int* in_sizes, int n_in,
                              void* d_out, int out_size, void* d_ws, size_t ws_size,
                              hipStream_t stream)
{
    const float* x      = (const float*)d_in[0];
    const float* scores = (const float*)d_in[1];
    const float* delta  = (const float*)d_in[2];
    const float* W1     = (const float*)d_in[3];
    const float* W2     = (const float*)d_in[4];
    const float* W3     = (const float*)d_in[5];
    const float* W4     = (const float*)d_in[6];
    float* out = (float*)d_out;

    char* ws = (char*)d_ws;
    __hip_bfloat16* xb  = (__hip_bfloat16*)(ws);                    // 512 KB
    __hip_bfloat16* h1b = (__hip_bfloat16*)(ws + 524288);           // 256 KB
    __hip_bfloat16* h2b = (__hip_bfloat16*)(ws + 786432);           // 2 MB
    __hip_bfloat16* h3b = (__hip_bfloat16*)(ws + 2883584);          // 256 KB
    float* P1 = (float*)(ws + 3145728);                             // 4 MB
    float* P3 = (float*)(ws + 7340032);                             // 4 MB
    float* P4 = (float*)(ws + 11534336);                            // 4 MB

    const float* d1 = delta;
    const float* d2 = d1 + (size_t)R_N * IN_N;
    const float* d3 = d2 + (size_t)H_N * R_N;
    const float* d4 = d3 + (size_t)R_N * H_N;

    // x -> bf16 (512 blocks)
    convert_bf16<<<dim3(B_N * IN_N / 2 / 256), dim3(256), 0, stream>>>(x, xb);

    // L1: K=4096, N=512, KS=8
    gemm_layer<IN_N, R_N, 8, true, false, false>
        <<<dim3(E_N * (R_N / 32) * 8), dim3(256), 0, stream>>>(xb, W1, d1, P1, nullptr);
    reduce_ks_bf16<8, B_N * R_N>
        <<<dim3(E_N * B_N * R_N / 256), dim3(256), 0, stream>>>(P1, h1b);

    // L2: K=512, N=4096, relu -> bf16
    gemm_layer<R_N, H_N, 1, false, true, true>
        <<<dim3(E_N * (H_N / 32)), dim3(256), 0, stream>>>(h1b, W2, d2, nullptr, h2b);

    // L3: K=4096, N=512, KS=8
    gemm_layer<H_N, R_N, 8, false, false, false>
        <<<dim3(E_N * (R_N / 32) * 8), dim3(256), 0, stream>>>(h2b, W3, d3, P3, nullptr);
    reduce_ks_bf16<8, B_N * R_N>
        <<<dim3(E_N * B_N * R_N / 256), dim3(256), 0, stream>>>(P3, h3b);

    // L4: K=512, N=4096
    gemm_layer<R_N, OUT_N, 1, false, false, false>
        <<<dim3(E_N * (OUT_N / 32)), dim3(256), 0, stream>>>(h3b, W4, d4, P4, nullptr);

    // out = sum_e scores[e] * P4[e]  (512 blocks)
    reduce_experts<<<dim3(B_N * OUT_N / 2 / 256), dim3(256), 0, stream>>>(P4, scores, out);
}